// Round 2
// baseline (351.289 us; speedup 1.0000x reference)
//
#include <hip/hip_runtime.h>
#include <cstddef>

namespace {

constexpr int B = 4, V = 20000, P = 400000, NN = 50000, MP = 32;
constexpr float GAMMA = 10.0f, INV_GAMMA = 0.1f;
constexpr float KSOFT = 2.0f;
constexpr float THRESH = 1.0f;
constexpr float W_WL = 1.0f, W_CONG = 0.5f;
constexpr int BLOCKS_PER_BATCH = 256;            // R2: 128 -> 256 (occupancy was grid-capped at 25%)
constexpr int NET_GRID = BLOCKS_PER_BATCH * B;   // 1024 blocks, 4 waves each

__device__ __forceinline__ float fast_rcp(float x) { return __builtin_amdgcn_rcpf(x); }
// sigmoid: inf-safe — exp overflow -> inf -> rcp -> 0
__device__ __forceinline__ float sigmoidf(float z) { return fast_rcp(1.0f + __expf(-z)); }

__global__ void zero_ws_kernel(float* __restrict__ p, int n) {
    int i = blockIdx.x * blockDim.x + threadIdx.x;
    if (i < n) p[i] = 0.0f;
}

// rotated = Rm @ off with Rm = [[w0-w2, w3-w1],[w1-w3, w0-w2]]
__global__ void pin_pos_kernel(const float* __restrict__ positions,
                               const int* __restrict__ pin_to_macro,
                               const float* __restrict__ pin_offsets,
                               const float* __restrict__ rot_onehot,
                               float* __restrict__ pin_pos) {
    int idx = blockIdx.x * blockDim.x + threadIdx.x;
    if (idx >= B * P) return;
    int b = idx / P;
    int p = idx - b * P;
    int m = pin_to_macro[p];
    float2 off = ((const float2*)pin_offsets)[p];
    float2 pos = ((const float2*)positions)[(size_t)b * V + m];
    float4 w = ((const float4*)rot_onehot)[(size_t)b * V + m];
    float a = w.x - w.z;   // w0 - w2
    float c = w.y - w.w;   // w1 - w3
    float rx = a * off.x - c * off.y;
    float ry = c * off.x + a * off.y;
    ((float2*)pin_pos)[idx] = make_float2(pos.x + rx, pos.y + ry);
}

// One wave per net. Lane i owns grid row i (y-index); 64-float register row acc.
__global__ void __launch_bounds__(256)
net_kernel(const float* __restrict__ pin_pos,
           const int* __restrict__ net_to_pin,
           const float* __restrict__ net_weights,
           float* __restrict__ rudy,    // B * 64 * 64
           float* __restrict__ hpwl) {  // B
    __shared__ float tile[64 * 65];     // stride 65 -> conflict-free ds_add
    __shared__ float4 xst[4][16];       // per-wave in_x staging (64 floats)
    __shared__ float hpred[4];

    int x = blockIdx.x;
    int xcd = x & 7;                    // round-robin dispatch heuristic
    int b = xcd >> 1;                   // batch -> XCD pair (L2 locality)
    int sub = ((x >> 3) << 1) | (xcd & 1);   // 0..BLOCKS_PER_BATCH-1
    int tid = threadIdx.x;
    int wave = tid >> 6;
    int lane = tid & 63;

    for (int k = tid; k < 64 * 65; k += 256) tile[k] = 0.0f;
    __syncthreads();

    float acc[64];
    #pragma unroll
    for (int j = 0; j < 64; ++j) acc[j] = 0.0f;
    float hp = 0.0f;

    const float2* pp = (const float2*)(pin_pos + (size_t)b * P * 2);
    float* xrow = (float*)xst[wave];

    const int wstride = BLOCKS_PER_BATCH * 4;
    for (int n = sub * 4 + wave; n < NN; n += wstride) {
        float w = net_weights[n];                    // hoisted, independent
        // ---- gather up to 32 pins (lanes 0-31) ----
        float px = 0.0f, py = 0.0f;
        bool valid = false;
        if (lane < MP) {
            int pi = net_to_pin[n * MP + lane];
            if (pi >= 0) {
                valid = true;
                float2 q = pp[pi];
                px = q.x; py = q.y;
            }
        }
        // ---- direct exp sums: gamma*x in [-10.4,10.4], exp fits fp32 easily.
        // No max-subtraction => these 4 chains are independent of the 4 minmax
        // chains below; wl = (log Se^{gx} + log Se^{-gx} + ...)/g, no (max-min) term.
        float ex1 = valid ? __expf(GAMMA * px)  : 0.0f;
        float ex2 = valid ? __expf(-GAMMA * px) : 0.0f;
        float ey1 = valid ? __expf(GAMMA * py)  : 0.0f;
        float ey2 = valid ? __expf(-GAMMA * py) : 0.0f;
        float vxmax = valid ? px : -1e30f;
        float vxmin = valid ? px :  1e30f;
        float vymax = valid ? py : -1e30f;
        float vymin = valid ? py :  1e30f;
        #pragma unroll
        for (int m = 32; m >= 1; m >>= 1) {
            vxmax = fmaxf(vxmax, __shfl_xor(vxmax, m, 64));
            vxmin = fminf(vxmin, __shfl_xor(vxmin, m, 64));
            vymax = fmaxf(vymax, __shfl_xor(vymax, m, 64));
            vymin = fminf(vymin, __shfl_xor(vymin, m, 64));
            ex1 += __shfl_xor(ex1, m, 64);
            ex2 += __shfl_xor(ex2, m, 64);
            ey1 += __shfl_xor(ey1, m, 64);
            ey2 += __shfl_xor(ey2, m, 64);
        }
        float wl = (__logf(ex1) + __logf(ex2) + __logf(ey1) + __logf(ey2)) * INV_GAMMA;
        hp += wl * w;

        // ---- bbox in grid coords; (v+1)*0.5*(M-1), M-1 = 63 ----
        float bxmin = (vxmin + 1.0f) * 31.5f;
        float bxmax = (vxmax + 1.0f) * 31.5f;
        float bymin = (vymin + 1.0f) * 31.5f;
        float bymax = (vymax + 1.0f) * 31.5f;
        float inv_size = fast_rcp(
            fmaxf((bxmax - bxmin + 1.0f) * (bymax - bymin + 1.0f), 1.0f));
        float g = (float)lane;
        float inx = sigmoidf(KSOFT * (g - bxmin + 0.5f)) * sigmoidf(KSOFT * (bxmax - g + 0.5f));
        float iny = sigmoidf(KSOFT * (g - bymin + 0.5f)) * sigmoidf(KSOFT * (bymax - g + 0.5f));
        float yv = iny * inv_size;

        // ---- outer product: acc[j] += yv * in_x[j], in_x broadcast via LDS ----
        xrow[lane] = inx;
        asm volatile("s_waitcnt lgkmcnt(0)" ::: "memory");  // wave-private LDS, no barrier needed
        #pragma unroll
        for (int jj = 0; jj < 16; ++jj) {
            float4 xv = xst[wave][jj];   // uniform address -> broadcast ds_read_b128
            acc[4 * jj + 0] = fmaf(yv, xv.x, acc[4 * jj + 0]);
            acc[4 * jj + 1] = fmaf(yv, xv.y, acc[4 * jj + 1]);
            acc[4 * jj + 2] = fmaf(yv, xv.z, acc[4 * jj + 2]);
            acc[4 * jj + 3] = fmaf(yv, xv.w, acc[4 * jj + 3]);
        }
    }

    // ---- block reduce: register rows -> LDS tile (stride-65 pad) ----
    #pragma unroll
    for (int j = 0; j < 64; ++j)
        atomicAdd(&tile[lane * 65 + j], acc[j]);
    if (lane == 0) hpred[wave] = hp;     // hp is wave-uniform
    __syncthreads();
    if (tid == 0)
        atomicAdd(&hpwl[b], hpred[0] + hpred[1] + hpred[2] + hpred[3]);
    for (int k = tid; k < 4096; k += 256) {
        int i = k >> 6, j = k & 63;
        atomicAdd(&rudy[(size_t)b * 4096 + k], tile[i * 65 + j]);
    }
}

__global__ void conv_penalty_kernel(const float* __restrict__ rudy,
                                    const float* __restrict__ hpwl,
                                    float* __restrict__ out) {
    int b = blockIdx.x;
    __shared__ float tile[64][64];
    __shared__ float ker[49];
    __shared__ float red[4];
    int tid = threadIdx.x;
    if (tid == 0) {
        float g1[7];
        for (int i = 0; i < 7; ++i) { float t = (float)(i - 3); g1[i] = __expf(-t * t / 4.5f); }
        float s = 0.0f;
        for (int i = 0; i < 7; ++i)
            for (int j = 0; j < 7; ++j) s += g1[i] * g1[j];
        float inv = 1.0f / s;
        for (int i = 0; i < 7; ++i)
            for (int j = 0; j < 7; ++j) ker[i * 7 + j] = g1[i] * g1[j] * inv;
    }
    for (int k = tid; k < 4096; k += 256) tile[k >> 6][k & 63] = rudy[b * 4096 + k];
    __syncthreads();
    float pen = 0.0f;
    for (int k = tid; k < 4096; k += 256) {
        int i = k >> 6, j = k & 63;
        float s = 0.0f;
        for (int di = -3; di <= 3; ++di) {
            int ii = i + di;
            if (ii < 0 || ii >= 64) continue;
            #pragma unroll
            for (int dj = -3; dj <= 3; ++dj) {
                int jj = j + dj;
                if (jj < 0 || jj >= 64) continue;
                s += ker[(di + 3) * 7 + (dj + 3)] * tile[ii][jj];
            }
        }
        float ov = s - THRESH;
        if (ov > 0.0f) pen += ov * ov;
    }
    #pragma unroll
    for (int m = 32; m >= 1; m >>= 1) pen += __shfl_xor(pen, m, 64);
    if ((tid & 63) == 0) red[tid >> 6] = pen;
    __syncthreads();
    if (tid == 0) out[b] = W_WL * hpwl[b] + W_CONG * (red[0] + red[1] + red[2] + red[3]);
}

} // namespace

extern "C" void kernel_launch(void* const* d_in, const int* in_sizes, int n_in,
                              void* d_out, int out_size, void* d_ws, size_t ws_size,
                              hipStream_t stream) {
    const float* positions    = (const float*)d_in[0];
    const int*   net_to_pin   = (const int*)d_in[1];
    const int*   pin_to_macro = (const int*)d_in[2];
    const float* pin_offsets  = (const float*)d_in[3];
    const float* rot_onehot   = (const float*)d_in[4];
    const float* net_weights  = (const float*)d_in[5];
    float* out = (float*)d_out;

    // workspace layout: pin_pos (B*P*2 f32 = 12.8 MB) | rudy (B*4096 f32) | hpwl (B f32)
    float* pin_pos = (float*)d_ws;
    float* rudy    = pin_pos + (size_t)B * P * 2;
    float* hpwl    = rudy + (size_t)B * 64 * 64;

    int nz = B * 64 * 64 + B;            // rudy + hpwl are contiguous
    zero_ws_kernel<<<(nz + 255) / 256, 256, 0, stream>>>(rudy, nz);
    pin_pos_kernel<<<(B * P + 255) / 256, 256, 0, stream>>>(
        positions, pin_to_macro, pin_offsets, rot_onehot, pin_pos);
    net_kernel<<<NET_GRID, 256, 0, stream>>>(pin_pos, net_to_pin, net_weights, rudy, hpwl);
    conv_penalty_kernel<<<B, 256, 0, stream>>>(rudy, hpwl, out);
}

// Round 3
// 277.594 us; speedup vs baseline: 1.2655x; 1.2655x over previous
//
#include <hip/hip_runtime.h>
#include <cstddef>

namespace {

constexpr int B = 4, V = 20000, P = 400000, NN = 50000, MP = 32;
constexpr float GAMMA = 10.0f, INV_GAMMA = 0.1f;
constexpr float KSOFT = 2.0f;
constexpr float THRESH = 1.0f;
constexpr float W_WL = 1.0f, W_CONG = 0.5f;
constexpr int BLOCKS_PER_BATCH = 256;
constexpr int NET_GRID = BLOCKS_PER_BATCH * B;   // 1024 blocks, 4 waves each

__device__ __forceinline__ float fast_rcp(float x) { return __builtin_amdgcn_rcpf(x); }
__device__ __forceinline__ float sigmoidf(float z) { return fast_rcp(1.0f + __expf(-z)); }

// ---- DPP wave64 reductions: pure VALU, no LDS pipe traffic ----
// update_dpp(old, src, ctrl, row_mask, bank_mask, bound_ctrl=false):
// invalid source lanes yield `old` (the op identity).
template <int CTRL>
__device__ __forceinline__ float dpp_mov(float x, float identity) {
    return __int_as_float(__builtin_amdgcn_update_dpp(
        __float_as_int(identity), __float_as_int(x), CTRL, 0xf, 0xf, false));
}
#define DPP_RED(x, OP, ID)                                   \
    x = OP(x, dpp_mov<0x111>(x, ID)); /* row_shr:1  */       \
    x = OP(x, dpp_mov<0x112>(x, ID)); /* row_shr:2  */       \
    x = OP(x, dpp_mov<0x114>(x, ID)); /* row_shr:4  */       \
    x = OP(x, dpp_mov<0x118>(x, ID)); /* row_shr:8  */       \
    x = OP(x, dpp_mov<0x142>(x, ID)); /* row_bcast:15 */     \
    x = OP(x, dpp_mov<0x143>(x, ID)); /* row_bcast:31 */     \
    x = __int_as_float(__builtin_amdgcn_readlane(__float_as_int(x), 63));

__device__ __forceinline__ float op_add(float a, float b) { return a + b; }

__global__ void zero_ws_kernel(float* __restrict__ p, int n) {
    int i = blockIdx.x * blockDim.x + threadIdx.x;
    if (i < n) p[i] = 0.0f;
}

// rotated = Rm @ off with Rm = [[w0-w2, w3-w1],[w1-w3, w0-w2]]
__global__ void pin_pos_kernel(const float* __restrict__ positions,
                               const int* __restrict__ pin_to_macro,
                               const float* __restrict__ pin_offsets,
                               const float* __restrict__ rot_onehot,
                               float* __restrict__ pin_pos) {
    int idx = blockIdx.x * blockDim.x + threadIdx.x;
    if (idx >= B * P) return;
    int b = idx / P;
    int p = idx - b * P;
    int m = pin_to_macro[p];
    float2 off = ((const float2*)pin_offsets)[p];
    float2 pos = ((const float2*)positions)[(size_t)b * V + m];
    float4 w = ((const float4*)rot_onehot)[(size_t)b * V + m];
    float a = w.x - w.z;
    float c = w.y - w.w;
    float rx = a * off.x - c * off.y;
    float ry = c * off.x + a * off.y;
    ((float2*)pin_pos)[idx] = make_float2(pos.x + rx, pos.y + ry);
}

// One wave per net. Lane i owns grid row i; 64-float register row acc.
// Inner loop uses NO LDS: DPP reductions + readlane broadcast.
__global__ void __launch_bounds__(256)
net_kernel(const float* __restrict__ pin_pos,
           const int* __restrict__ net_to_pin,
           const float* __restrict__ net_weights,
           float* __restrict__ rudy,    // B * 64 * 64
           float* __restrict__ hpwl) {  // B
    __shared__ float tile[64 * 65];     // stride 65 -> conflict-free ds_add (epilogue only)
    __shared__ float hpred[4];

    int x = blockIdx.x;
    int xcd = x & 7;
    int b = xcd >> 1;                   // batch -> XCD pair (L2 locality)
    int sub = ((x >> 3) << 1) | (xcd & 1);
    int tid = threadIdx.x;
    int wave = tid >> 6;
    int lane = tid & 63;

    for (int k = tid; k < 64 * 65; k += 256) tile[k] = 0.0f;
    __syncthreads();

    float acc[64];
    #pragma unroll
    for (int j = 0; j < 64; ++j) acc[j] = 0.0f;
    float hp = 0.0f;

    const float2* pp = (const float2*)(pin_pos + (size_t)b * P * 2);

    const int wstride = BLOCKS_PER_BATCH * 4;
    for (int n = sub * 4 + wave; n < NN; n += wstride) {
        float w = net_weights[n];
        // ---- gather up to 32 pins (lanes 0-31) ----
        float px = 0.0f, py = 0.0f;
        bool valid = false;
        if (lane < MP) {
            int pi = net_to_pin[n * MP + lane];
            if (pi >= 0) {
                valid = true;
                float2 q = pp[pi];
                px = q.x; py = q.y;
            }
        }
        // gamma*x in [-10.4,10.4]: direct exp fits fp32, no max-subtraction.
        float ex1 = valid ? __expf(GAMMA * px)  : 0.0f;
        float ex2 = valid ? __expf(-GAMMA * px) : 0.0f;
        float ey1 = valid ? __expf(GAMMA * py)  : 0.0f;
        float ey2 = valid ? __expf(-GAMMA * py) : 0.0f;
        float vxmax = valid ? px : -1e30f;
        float vxmin = valid ? px :  1e30f;
        float vymax = valid ? py : -1e30f;
        float vymin = valid ? py :  1e30f;

        DPP_RED(ex1, op_add, 0.0f);
        DPP_RED(ex2, op_add, 0.0f);
        DPP_RED(ey1, op_add, 0.0f);
        DPP_RED(ey2, op_add, 0.0f);
        DPP_RED(vxmax, fmaxf, -1e30f);
        DPP_RED(vxmin, fminf,  1e30f);
        DPP_RED(vymax, fmaxf, -1e30f);
        DPP_RED(vymin, fminf,  1e30f);

        // log(a)+log(b)+log(c)+log(d) = log(a*b*c*d); product in [1e-18,1e24] - fp32 safe
        float wl = __logf(ex1 * ex2 * ey1 * ey2) * INV_GAMMA;
        hp += wl * w;

        // ---- bbox in grid coords; (v+1)*0.5*(M-1), M-1 = 63 ----
        float bxmin = (vxmin + 1.0f) * 31.5f;
        float bxmax = (vxmax + 1.0f) * 31.5f;
        float bymin = (vymin + 1.0f) * 31.5f;
        float bymax = (vymax + 1.0f) * 31.5f;
        float inv_size = fast_rcp(
            fmaxf((bxmax - bxmin + 1.0f) * (bymax - bymin + 1.0f), 1.0f));
        float g = (float)lane;
        float inx = sigmoidf(KSOFT * (g - bxmin + 0.5f)) * sigmoidf(KSOFT * (bxmax - g + 0.5f));
        float iny = sigmoidf(KSOFT * (g - bymin + 0.5f)) * sigmoidf(KSOFT * (bymax - g + 0.5f));
        float yv = iny * inv_size;

        // ---- outer product via readlane broadcast: pure VALU, no LDS ----
        int inx_i = __float_as_int(inx);
        #pragma unroll
        for (int j = 0; j < 64; ++j) {
            float xj = __int_as_float(__builtin_amdgcn_readlane(inx_i, j));
            acc[j] = fmaf(yv, xj, acc[j]);
        }
    }

    // ---- block reduce: register rows -> LDS tile (stride-65 pad) ----
    #pragma unroll
    for (int j = 0; j < 64; ++j)
        atomicAdd(&tile[lane * 65 + j], acc[j]);
    if (lane == 0) hpred[wave] = hp;     // hp is wave-uniform
    __syncthreads();
    if (tid == 0)
        atomicAdd(&hpwl[b], hpred[0] + hpred[1] + hpred[2] + hpred[3]);
    for (int k = tid; k < 4096; k += 256) {
        int i = k >> 6, j = k & 63;
        atomicAdd(&rudy[(size_t)b * 4096 + k], tile[i * 65 + j]);
    }
}

__global__ void conv_penalty_kernel(const float* __restrict__ rudy,
                                    const float* __restrict__ hpwl,
                                    float* __restrict__ out) {
    int b = blockIdx.x;
    __shared__ float tile[64][64];
    __shared__ float ker[49];
    __shared__ float red[4];
    int tid = threadIdx.x;
    if (tid == 0) {
        float g1[7];
        for (int i = 0; i < 7; ++i) { float t = (float)(i - 3); g1[i] = __expf(-t * t / 4.5f); }
        float s = 0.0f;
        for (int i = 0; i < 7; ++i)
            for (int j = 0; j < 7; ++j) s += g1[i] * g1[j];
        float inv = 1.0f / s;
        for (int i = 0; i < 7; ++i)
            for (int j = 0; j < 7; ++j) ker[i * 7 + j] = g1[i] * g1[j] * inv;
    }
    for (int k = tid; k < 4096; k += 256) tile[k >> 6][k & 63] = rudy[b * 4096 + k];
    __syncthreads();
    float pen = 0.0f;
    for (int k = tid; k < 4096; k += 256) {
        int i = k >> 6, j = k & 63;
        float s = 0.0f;
        for (int di = -3; di <= 3; ++di) {
            int ii = i + di;
            if (ii < 0 || ii >= 64) continue;
            #pragma unroll
            for (int dj = -3; dj <= 3; ++dj) {
                int jj = j + dj;
                if (jj < 0 || jj >= 64) continue;
                s += ker[(di + 3) * 7 + (dj + 3)] * tile[ii][jj];
            }
        }
        float ov = s - THRESH;
        if (ov > 0.0f) pen += ov * ov;
    }
    #pragma unroll
    for (int m = 32; m >= 1; m >>= 1) pen += __shfl_xor(pen, m, 64);
    if ((tid & 63) == 0) red[tid >> 6] = pen;
    __syncthreads();
    if (tid == 0) out[b] = W_WL * hpwl[b] + W_CONG * (red[0] + red[1] + red[2] + red[3]);
}

} // namespace

extern "C" void kernel_launch(void* const* d_in, const int* in_sizes, int n_in,
                              void* d_out, int out_size, void* d_ws, size_t ws_size,
                              hipStream_t stream) {
    const float* positions    = (const float*)d_in[0];
    const int*   net_to_pin   = (const int*)d_in[1];
    const int*   pin_to_macro = (const int*)d_in[2];
    const float* pin_offsets  = (const float*)d_in[3];
    const float* rot_onehot   = (const float*)d_in[4];
    const float* net_weights  = (const float*)d_in[5];
    float* out = (float*)d_out;

    float* pin_pos = (float*)d_ws;
    float* rudy    = pin_pos + (size_t)B * P * 2;
    float* hpwl    = rudy + (size_t)B * 64 * 64;

    int nz = B * 64 * 64 + B;
    zero_ws_kernel<<<(nz + 255) / 256, 256, 0, stream>>>(rudy, nz);
    pin_pos_kernel<<<(B * P + 255) / 256, 256, 0, stream>>>(
        positions, pin_to_macro, pin_offsets, rot_onehot, pin_pos);
    net_kernel<<<NET_GRID, 256, 0, stream>>>(pin_pos, net_to_pin, net_weights, rudy, hpwl);
    conv_penalty_kernel<<<B, 256, 0, stream>>>(rudy, hpwl, out);
}

// Round 4
// 253.085 us; speedup vs baseline: 1.3880x; 1.0968x over previous
//
#include <hip/hip_runtime.h>
#include <cstddef>

namespace {

constexpr int B = 4, V = 20000, P = 400000, NN = 50000, MP = 32;
constexpr float GAMMA = 10.0f, INV_GAMMA = 0.1f;
constexpr float KSOFT = 2.0f;
constexpr float THRESH = 1.0f;
constexpr float W_WL = 1.0f, W_CONG = 0.5f;
constexpr int BLOCKS_PER_BATCH = 256;
constexpr int NET_GRID = BLOCKS_PER_BATCH * B;   // 1024 blocks, 4 waves each

typedef __attribute__((ext_vector_type(8)))  short bf16x8;
typedef __attribute__((ext_vector_type(16))) float f32x16;

__device__ __forceinline__ float fast_rcp(float x) { return __builtin_amdgcn_rcpf(x); }
__device__ __forceinline__ float sigmoidf(float z) { return fast_rcp(1.0f + __expf(-z)); }
__device__ __forceinline__ short f2bf(float f) {   // fp32 -> bf16 RN
    unsigned u = __float_as_uint(f);
    u += 0x7fffu + ((u >> 16) & 1u);
    return (short)(u >> 16);
}
template <int CTRL>
__device__ __forceinline__ float dpp_mov(float x, float id) {
    return __int_as_float(__builtin_amdgcn_update_dpp(
        __float_as_int(id), __float_as_int(x), CTRL, 0xf, 0xf, false));
}
__device__ __forceinline__ float rdlane(float x, int l) {
    return __int_as_float(__builtin_amdgcn_readlane(__float_as_int(x), l));
}
// 5-stage half-wave reduction: lane31 = red(lanes 0-31), lane63 = red(lanes 32-63)
#define DPP5(x, OP, ID)                              \
    x = OP(x, dpp_mov<0x111>(x, ID)); /* shr:1  */   \
    x = OP(x, dpp_mov<0x112>(x, ID)); /* shr:2  */   \
    x = OP(x, dpp_mov<0x114>(x, ID)); /* shr:4  */   \
    x = OP(x, dpp_mov<0x118>(x, ID)); /* shr:8  */   \
    x = OP(x, dpp_mov<0x142>(x, ID)); /* bcast:15 */
__device__ __forceinline__ float op_add(float a, float b) { return a + b; }

__global__ void zero_ws_kernel(float* __restrict__ p, int n) {
    int i = blockIdx.x * blockDim.x + threadIdx.x;
    if (i < n) p[i] = 0.0f;
}

// per-(b,v): pack pos.x, pos.y, a=w0-w2, c=w1-w3 into one float4 (one gather in pin_pos)
__global__ void macro_prep_kernel(const float* __restrict__ positions,
                                  const float* __restrict__ rot_onehot,
                                  float4* __restrict__ mac) {
    int i = blockIdx.x * blockDim.x + threadIdx.x;
    if (i >= B * V) return;
    float2 pos = ((const float2*)positions)[i];
    float4 w = ((const float4*)rot_onehot)[i];
    mac[i] = make_float4(pos.x, pos.y, w.x - w.z, w.y - w.w);
}

__global__ void pin_pos_kernel(const float4* __restrict__ mac,
                               const int* __restrict__ pin_to_macro,
                               const float* __restrict__ pin_offsets,
                               float* __restrict__ pin_pos) {
    int idx = blockIdx.x * blockDim.x + threadIdx.x;
    if (idx >= B * P) return;
    int b = idx / P;
    int p = idx - b * P;
    int m = pin_to_macro[p];
    float2 off = ((const float2*)pin_offsets)[p];
    float4 md = mac[(size_t)b * V + m];
    ((float2*)pin_pos)[idx] = make_float2(md.x + md.z * off.x - md.w * off.y,
                                          md.y + md.w * off.x + md.z * off.y);
}

// One wave per net-stream. Inner loop: half-wave DPP reductions (x in lanes 0-31,
// y in lanes 32-63), per-lane sigmoid profiles, then rank-16 MFMA accumulation
// of rudy += Y^T X (K = nets) on the matrix pipe.
__global__ void __launch_bounds__(256)
net_kernel(const float* __restrict__ pin_pos,
           const int* __restrict__ net_to_pin,
           const float* __restrict__ net_weights,
           float* __restrict__ rudy,    // B * 64 * 64
           float* __restrict__ hpwl) {  // B
    __shared__ float tile[64 * 65];
    __shared__ float hpred[4];

    int x = blockIdx.x;
    int xcd = x & 7;
    int b = xcd >> 1;                   // batch -> XCD pair (L2 locality)
    int sub = ((x >> 3) << 1) | (xcd & 1);
    int tid = threadIdx.x;
    int wave = tid >> 6;
    int lane = tid & 63;
    bool lo = lane < 32;
    float g = (float)lane;

    for (int k = tid; k < 64 * 65; k += 256) tile[k] = 0.0f;
    __syncthreads();

    f32x16 acc00, acc01, acc10, acc11;
    #pragma unroll
    for (int r = 0; r < 16; ++r) { acc00[r] = 0.f; acc01[r] = 0.f; acc10[r] = 0.f; acc11[r] = 0.f; }
    float hp = 0.0f;

    const float2* pp = (const float2*)(pin_pos + (size_t)b * P * 2);
    const int wstride = BLOCKS_PER_BATCH * 4;
    int n0 = sub * 4 + wave;

    for (int grp = 0; grp < 4; ++grp) {          // 4 groups of 16 covers <=49 nets/wave
        float xr[16], yr[16];
        #pragma unroll
        for (int t = 0; t < 16; ++t) {
            int nt = n0 + (grp * 16 + t) * wstride;   // wave-uniform
            float xv = 0.0f, yv = 0.0f;
            if (nt < NN) {
                float w = net_weights[nt];
                int pi = net_to_pin[nt * MP + (lane & 31)];  // both halves load same pins
                bool valid = pi >= 0;
                float2 q = make_float2(0.f, 0.f);
                if (valid) q = pp[pi];
                float pxy = lo ? q.x : q.y;       // x in lanes 0-31, y in lanes 32-63
                float cmx = valid ? pxy : -1e30f;
                float cmn = valid ? pxy :  1e30f;
                float ce1 = valid ? __expf(GAMMA * pxy) : 0.0f;
                float ce2 = valid ? fast_rcp(ce1) : 0.0f;   // e^{-gx} = 1/e^{gx}
                DPP5(ce1, op_add, 0.0f);
                DPP5(ce2, op_add, 0.0f);
                DPP5(cmx, fmaxf, -1e30f);
                DPP5(cmn, fminf,  1e30f);
                float sx1 = rdlane(ce1, 31), sy1 = rdlane(ce1, 63);
                float sx2 = rdlane(ce2, 31), sy2 = rdlane(ce2, 63);
                float vxmax = rdlane(cmx, 31), vymax = rdlane(cmx, 63);
                float vxmin = rdlane(cmn, 31), vymin = rdlane(cmn, 63);
                hp += __logf(sx1 * sx2 * sy1 * sy2) * INV_GAMMA * w;

                float bxmin = (vxmin + 1.0f) * 31.5f;
                float bxmax = (vxmax + 1.0f) * 31.5f;
                float bymin = (vymin + 1.0f) * 31.5f;
                float bymax = (vymax + 1.0f) * 31.5f;
                float inv_size = fast_rcp(
                    fmaxf((bxmax - bxmin + 1.0f) * (bymax - bymin + 1.0f), 1.0f));
                xv = sigmoidf(KSOFT * (g - bxmin + 0.5f)) * sigmoidf(KSOFT * (bxmax - g + 0.5f));
                float iny = sigmoidf(KSOFT * (g - bymin + 0.5f)) * sigmoidf(KSOFT * (bymax - g + 0.5f));
                yv = iny * inv_size;
            }
            xr[t] = xv; yr[t] = yv;
        }
        // ---- build MFMA fragments: A = Y^T (M=row i, K=net), B = X (K=net, N=col j)
        // 32x32x16 layout: lane l holds m/n = l&31, k = (l>>5)*8 + j (A/B symmetric, so
        // any within-lane k-permutation cancels in the contraction).
        bf16x8 a0, a1, b0, b1;
        #pragma unroll
        for (int j = 0; j < 8; ++j) {
            float syl = __shfl_xor(yr[j],     32, 64);
            float syh = __shfl_xor(yr[j + 8], 32, 64);
            float sxl = __shfl_xor(xr[j],     32, 64);
            float sxh = __shfl_xor(xr[j + 8], 32, 64);
            a0[j] = f2bf(lo ? yr[j] : syh);      // rows 0-31
            a1[j] = f2bf(lo ? syl : yr[j + 8]);  // rows 32-63
            b0[j] = f2bf(lo ? xr[j] : sxh);      // cols 0-31
            b1[j] = f2bf(lo ? sxl : xr[j + 8]);  // cols 32-63
        }
        acc00 = __builtin_amdgcn_mfma_f32_32x32x16_bf16(a0, b0, acc00, 0, 0, 0);
        acc01 = __builtin_amdgcn_mfma_f32_32x32x16_bf16(a0, b1, acc01, 0, 0, 0);
        acc10 = __builtin_amdgcn_mfma_f32_32x32x16_bf16(a1, b0, acc10, 0, 0, 0);
        acc11 = __builtin_amdgcn_mfma_f32_32x32x16_bf16(a1, b1, acc11, 0, 0, 0);
    }

    // ---- epilogue: C/D layout col=lane&31, row=(r&3)+8*(r>>2)+4*(lane>>5)
    int col = lane & 31, rq = lane >> 5;
    #pragma unroll
    for (int r = 0; r < 16; ++r) {
        int row = (r & 3) + 8 * (r >> 2) + 4 * rq;
        atomicAdd(&tile[row * 65 + col],             acc00[r]);
        atomicAdd(&tile[row * 65 + col + 32],        acc01[r]);
        atomicAdd(&tile[(row + 32) * 65 + col],      acc10[r]);
        atomicAdd(&tile[(row + 32) * 65 + col + 32], acc11[r]);
    }
    if (lane == 0) hpred[wave] = hp;     // hp is wave-uniform
    __syncthreads();
    if (tid == 0)
        atomicAdd(&hpwl[b], hpred[0] + hpred[1] + hpred[2] + hpred[3]);
    for (int k = tid; k < 4096; k += 256) {
        int i = k >> 6, j = k & 63;
        atomicAdd(&rudy[(size_t)b * 4096 + k], tile[i * 65 + j]);
    }
}

__global__ void conv_penalty_kernel(const float* __restrict__ rudy,
                                    const float* __restrict__ hpwl,
                                    float* __restrict__ out) {
    int b = blockIdx.x;
    __shared__ float tile[64][64];
    __shared__ float ker[49];
    __shared__ float red[4];
    int tid = threadIdx.x;
    if (tid == 0) {
        float g1[7];
        for (int i = 0; i < 7; ++i) { float t = (float)(i - 3); g1[i] = __expf(-t * t / 4.5f); }
        float s = 0.0f;
        for (int i = 0; i < 7; ++i)
            for (int j = 0; j < 7; ++j) s += g1[i] * g1[j];
        float inv = 1.0f / s;
        for (int i = 0; i < 7; ++i)
            for (int j = 0; j < 7; ++j) ker[i * 7 + j] = g1[i] * g1[j] * inv;
    }
    for (int k = tid; k < 4096; k += 256) tile[k >> 6][k & 63] = rudy[b * 4096 + k];
    __syncthreads();
    float pen = 0.0f;
    for (int k = tid; k < 4096; k += 256) {
        int i = k >> 6, j = k & 63;
        float s = 0.0f;
        for (int di = -3; di <= 3; ++di) {
            int ii = i + di;
            if (ii < 0 || ii >= 64) continue;
            #pragma unroll
            for (int dj = -3; dj <= 3; ++dj) {
                int jj = j + dj;
                if (jj < 0 || jj >= 64) continue;
                s += ker[(di + 3) * 7 + (dj + 3)] * tile[ii][jj];
            }
        }
        float ov = s - THRESH;
        if (ov > 0.0f) pen += ov * ov;
    }
    #pragma unroll
    for (int m = 32; m >= 1; m >>= 1) pen += __shfl_xor(pen, m, 64);
    if ((tid & 63) == 0) red[tid >> 6] = pen;
    __syncthreads();
    if (tid == 0) out[b] = W_WL * hpwl[b] + W_CONG * (red[0] + red[1] + red[2] + red[3]);
}

} // namespace

extern "C" void kernel_launch(void* const* d_in, const int* in_sizes, int n_in,
                              void* d_out, int out_size, void* d_ws, size_t ws_size,
                              hipStream_t stream) {
    const float* positions    = (const float*)d_in[0];
    const int*   net_to_pin   = (const int*)d_in[1];
    const int*   pin_to_macro = (const int*)d_in[2];
    const float* pin_offsets  = (const float*)d_in[3];
    const float* rot_onehot   = (const float*)d_in[4];
    const float* net_weights  = (const float*)d_in[5];
    float* out = (float*)d_out;

    // ws: pin_pos (12.8MB) | rudy (64KB) | hpwl | mac (1.28MB)
    float* pin_pos = (float*)d_ws;
    float* rudy    = pin_pos + (size_t)B * P * 2;
    float* hpwl    = rudy + (size_t)B * 64 * 64;
    float4* mac    = (float4*)(hpwl + B);

    int nz = B * 64 * 64 + B;
    zero_ws_kernel<<<(nz + 255) / 256, 256, 0, stream>>>(rudy, nz);
    macro_prep_kernel<<<(B * V + 255) / 256, 256, 0, stream>>>(positions, rot_onehot, mac);
    pin_pos_kernel<<<(B * P + 255) / 256, 256, 0, stream>>>(mac, pin_to_macro, pin_offsets, pin_pos);
    net_kernel<<<NET_GRID, 256, 0, stream>>>(pin_pos, net_to_pin, net_weights, rudy, hpwl);
    conv_penalty_kernel<<<B, 256, 0, stream>>>(rudy, hpwl, out);
}